// Round 10
// baseline (428.007 us; speedup 1.0000x reference)
//
#include <hip/hip_runtime.h>

#define N_NODES 100000
#define N_EDGES 400000
#define N_GRAPHS 2048
#define HID 128
#define NLAYER 4
#define TOUT 5
#define EPSV 1e-5f
#define SLOPE 0.2f
#define NB 98   // (N_NODES+1023)/1024
#define GEMM_BLOCKS 1563  // ceil(N_NODES/64)
#define AGGR_BLOCKS 12500 // N_NODES/8
#define HINIT_BLOCKS 25000 // N_NODES/4

typedef float v4f __attribute__((ext_vector_type(4)));
typedef float v2f __attribute__((ext_vector_type(2)));
typedef __bf16 v8bf __attribute__((ext_vector_type(8)));

static __device__ __forceinline__ unsigned short f2bf_bits(float f){
  unsigned u = __builtin_bit_cast(unsigned, f);
  unsigned r = u + 0x7fffu + ((u >> 16) & 1u);
  return (unsigned short)(r >> 16);
}
static __device__ __forceinline__ float bfbits2f(unsigned short s){
  unsigned u = ((unsigned)s) << 16;
  return __builtin_bit_cast(float, u);
}
static __device__ __forceinline__ float bflo(unsigned u){
  return __builtin_bit_cast(float, u << 16);
}
static __device__ __forceinline__ float bfhi(unsigned u){
  return __builtin_bit_cast(float, u & 0xffff0000u);
}
static __device__ __forceinline__ float lrelu(float v){
  return v>0.f ? v : SLOPE*v;
}

// Bijective XCD-chunk swizzle (m204). Kept: null-but-harmless.
static __device__ __forceinline__ int xcd_chunk(int bid, int nwg){
  int q = nwg >> 3, r = nwg & 7;
  int x = bid & 7, i = bid >> 3;
  return (x < r ? x*(q+1) : r*(q+1) + (x - r)*q) + i;
}

// Physical bf16 layout (head-aligned pairing):
//   word u (0..63): b=u>>4, r=u&15 -> holds channels (b*32+r [lo], b*32+16+r [hi]).
//   Lane l (words 2l,2l+1) is entirely head l>>3.
//   contraction position for channel k: kp = (k>>5)*32 + (k&15)*2 + ((k>>4)&1).

// merged setup:
//  blocks 0..15      : mebuf direct (wave-per-output, parallel)
//  block  16         : BN fold
//  blocks 17..1040   : w_ext (split hi/lo)
//  blocks 1041..1296 : wswz (single bf16 W)
//  blocks 1297..1687 : zero deg/fill
//  blocks 1688..     : hinit (XCD-chunk swizzled)
__global__ void k_setup(const float* __restrict__ gat_edge_w, const float* __restrict__ att_edge,
                        const float* __restrict__ edge_w, const float* __restrict__ edge_b,
                        const float* __restrict__ gat_bias, const float* __restrict__ gamma,
                        const float* __restrict__ beta, const float* __restrict__ mean,
                        const float* __restrict__ var, const float* __restrict__ gat_lin_w,
                        const float* __restrict__ att_src, const float* __restrict__ att_dst,
                        const float* __restrict__ x, const float* __restrict__ nw,
                        const float* __restrict__ nb, unsigned* __restrict__ h16,
                        float* __restrict__ mebuf, float* __restrict__ bnA, float* __restrict__ bnS,
                        unsigned short* __restrict__ whiE, unsigned short* __restrict__ wloE,
                        unsigned short* __restrict__ whi,
                        int* __restrict__ deg, int* __restrict__ fill){
  int bid = blockIdx.x, t = threadIdx.x;
  if(bid < 16){
    // mebuf[o], o = bid*4 + wave; o<48: edge_w row f=o>>4; o>=48: edge_b
    int wv = t>>6, lane = t&63;
    int o = bid*4 + wv;
    int li = (o<48)? (o&15) : (o-48);
    int f = o>>4;
    int l = li>>2, hh = li&3;
    int c = lane&31, kk = lane>>5;
    float at_c = att_edge[l*128 + hh*32 + c];
    float acc = 0.f;
    #pragma unroll 8
    for(int t2=0; t2<64; ++t2){
      int k = kk*64 + t2;
      float wk = (o<48)? edge_w[f*128+k] : edge_b[k];
      acc += wk * gat_edge_w[l*16384 + k*128 + hh*32 + c];
    }
    acc *= at_c;
    acc += __shfl_xor(acc,1); acc += __shfl_xor(acc,2); acc += __shfl_xor(acc,4);
    acc += __shfl_xor(acc,8); acc += __shfl_xor(acc,16); acc += __shfl_xor(acc,32);
    if(lane==0) mebuf[o] = acc;
  } else if(bid == 16){
    for(int i=t; i<NLAYER*HID; i+=256){
      int l_ = i>>7, pos = i&127, lane = pos>>2, j = pos&3;
      int ch = ((lane>>3)<<5) + ((lane&7)<<1) + ((j&1)<<4) + (j>>1);
      int src = l_*128 + ch;
      float A = gamma[src]*rsqrtf(var[src]+EPSV);
      bnA[i] = A;
      bnS[i] = (gat_bias[src]-mean[src])*A + beta[src];
    }
  } else if(bid <= 1040){
    int wave = t>>6, lane = t&63;
    int i = (bid-17)*8 + wave*2 + (lane>>5);   // 0..8191
    int l_ = i>>11, rest = i&2047, kp = rest>>4, col = rest&15;
    int sub = lane&31;
    float val = 0.f;
    if(col < 8){
      int h_ = col&3, isdst = col>>2;
      int ch = ((kp>>5)<<5) + ((kp&1)<<4) + ((kp&31)>>1);
      const float* at = (isdst? att_dst : att_src);
      val = gat_lin_w[l_*16384 + ch*128 + h_*32 + sub] * at[l_*128 + h_*32 + sub];
    }
    val += __shfl_xor(val,1); val += __shfl_xor(val,2); val += __shfl_xor(val,4);
    val += __shfl_xor(val,8); val += __shfl_xor(val,16);
    if(sub == 0){
      unsigned short hi = f2bf_bits(val);
      unsigned short lo = f2bf_bits(val - bfbits2f(hi));
      int kb=kp>>5, quad=(kp>>3)&3, jj=kp&7, lane2=quad*16+col;
      int dst = ((l_*4+kb)*64 + lane2)*8 + jj;
      whiE[dst]=hi; wloE[dst]=lo;
    }
  } else if(bid <= 1296){
    int tg = (bid-1041)*256 + t;              // 0..65535 == dst index
    int base = tg>>9, off = tg&511;
    int l = base>>5, kb=(base>>3)&3, cg=base&7;
    int lane = off>>3, j = off&7;
    int quad = lane>>4, r = lane&15;
    int kp = kb*32 + quad*8 + j;
    int k = ((kp>>5)<<5) | ((kp&1)<<4) | ((kp&31)>>1);
    whi[tg] = f2bf_bits(gat_lin_w[l*16384 + k*128 + cg*16 + r]);
  } else if(bid <= 1687){
    int tg = (bid-1297)*256 + t;
    if(tg < N_NODES){ deg[tg]=0; fill[tg]=0; }
  } else {
    int j = bid - 1688;
    int node = xcd_chunk(j, HINIT_BLOCKS)*4 + (t>>6);
    int c = t&63;
    int ch = ((c>>4)<<5) + (c&15);
    float a0 = nb[ch], a1 = nb[ch+16];
    #pragma unroll
    for(int f=0; f<7; ++f){
      float xv = x[node*7+f];
      a0 += xv*nw[f*HID+ch];
      a1 += xv*nw[f*HID+ch+16];
    }
    unsigned p = (unsigned)f2bf_bits(a0) | ((unsigned)f2bf_bits(a1)<<16);
    h16[(size_t)node*64 + c] = p;
  }
}

// deg count only (after zeroing in k_setup)
__global__ void k_deg(const int* __restrict__ ei, int* __restrict__ deg){
  int e = blockIdx.x*256 + threadIdx.x;
  if(e < N_EDGES) atomicAdd(&deg[ei[N_EDGES+e]], 1);
}

// scan phase 1: per-chunk sums
__global__ void k_scan1(const int* __restrict__ deg, int* __restrict__ part){
  __shared__ int s[256];
  int t=threadIdx.x; int base = blockIdx.x*1024 + t*4;
  int sum=0;
  #pragma unroll
  for(int j=0;j<4;++j){ int i=base+j; sum += (i<N_NODES)? deg[i]:0; }
  s[t]=sum; __syncthreads();
  for(int off=128; off>0; off>>=1){ if(t<off) s[t]+=s[t+off]; __syncthreads(); }
  if(t==0) part[blockIdx.x]=s[0];
}
// scan phase 2+3 fused
__global__ void k_scan3(const int* __restrict__ deg, const int* __restrict__ part,
                        int* __restrict__ rowptr){
  __shared__ int s[256];
  int t=threadIdx.x, b=blockIdx.x;
  int g = 0, tot = 0;
  for(int i=0;i<NB;++i){ int v = part[i]; g += (i<b)? v : 0; tot += v; }
  if(b==0 && t==0) rowptr[N_NODES]=tot;
  int base = b*1024 + t*4;
  int v[4]; int sum=0; int pre[4];
  #pragma unroll
  for(int j=0;j<4;++j){ int i=base+j; v[j]=(i<N_NODES)?deg[i]:0; pre[j]=sum; sum+=v[j]; }
  s[t]=sum; __syncthreads();
  for(int off=1; off<256; off<<=1){
    int xv = (t>=off)? s[t-off]:0; __syncthreads();
    s[t]+=xv; __syncthreads();
  }
  int toff = (t>0)? s[t-1]:0;
  #pragma unroll
  for(int j=0;j<4;++j){ int i=base+j; if(i<N_NODES) rowptr[i]=g+toff+pre[j]; }
}

// xh = h16 @ W[l]. 64 rows/block, one 16-row tile per wave. Weights (40KB)
// staged into LDS once per block; MFMA reads via ds_read_b128. LDS-free xhb
// epilogue (full-line stores); asad via 512B wave-private LDS transpose.
// Layer-0 launch carries CSR-build tail blocks.
__global__ void k_gemm(const unsigned short* __restrict__ h16,
                       const unsigned short* __restrict__ whi,
                       const unsigned short* __restrict__ whiE,
                       const unsigned short* __restrict__ wloE,
                       unsigned* __restrict__ xhb, float* __restrict__ asad,
                       const int* __restrict__ ei, const float* __restrict__ ea,
                       const int* __restrict__ rowptr, int* __restrict__ fill,
                       int* __restrict__ csr_src, float* __restrict__ ea_csr){
  if(blockIdx.x >= GEMM_BLOCKS){
    int e = (blockIdx.x - GEMM_BLOCKS)*256 + threadIdx.x;
    if(e < N_EDGES){
      int dst = ei[N_EDGES+e];
      int pos = rowptr[dst] + atomicAdd(&fill[dst],1);
      csr_src[pos] = ei[e];
      v4f q = {ea[e*3], ea[e*3+1], ea[e*3+2], 0.f};
      ((v4f*)ea_csr)[pos] = q;
    }
    return;
  }
  __shared__ uint4 whi_s4[2048];   // 32KB
  __shared__ uint4 wE_s4[256];     // 4KB
  __shared__ uint4 wL_s4[256];     // 4KB
  __shared__ float asbuf[4][128];
  int t = threadIdx.x;
  int wave = t>>6, lane = t&63;
  int q = lane>>4, r = lane&15;
  int wb = xcd_chunk(blockIdx.x, GEMM_BLOCKS);
  int r0 = wb*64 + wave*16;
  if(r0 > N_NODES-16) r0 = N_NODES-16;

  // ---- cooperative weight staging (coalesced, fully pipelined) ----
  {
    const uint4* s4 = (const uint4*)whi;
    #pragma unroll
    for(int i=0;i<8;++i) whi_s4[i*256+t] = s4[i*256+t];
    wE_s4[t] = ((const uint4*)whiE)[t];
    wL_s4[t] = ((const uint4*)wloE)[t];
  }

  v8bf av[4];
  {
    const unsigned short* hrow = h16 + (size_t)(r0 + r)*HID;
    #pragma unroll
    for(int kb=0;kb<4;++kb)
      av[kb] = *(const v8bf*)(hrow + kb*32 + q*8);
  }
  __syncthreads();

  const unsigned short* whi_s = (const unsigned short*)whi_s4;
  const unsigned short* whiE_s = (const unsigned short*)wE_s4;
  const unsigned short* wloE_s = (const unsigned short*)wL_s4;

  v4f acc[8];
  #pragma unroll
  for(int cg=0;cg<8;++cg){
    v4f a0 = {0.f,0.f,0.f,0.f};
    #pragma unroll
    for(int kb=0;kb<4;++kb){
      v8bf bhi = *(const v8bf*)(whi_s + ((kb*8+cg)*64 + lane)*8);
      a0 = __builtin_amdgcn_mfma_f32_16x16x32_bf16(av[kb], bhi, a0, 0,0,0);
    }
    acc[cg]=a0;
  }
  v4f acc8 = {0.f,0.f,0.f,0.f};
  #pragma unroll
  for(int kb=0;kb<4;++kb){
    v8bf bhi = *(const v8bf*)(whiE_s + (kb*64 + lane)*8);
    v8bf blo = *(const v8bf*)(wloE_s + (kb*64 + lane)*8);
    acc8 = __builtin_amdgcn_mfma_f32_16x16x32_bf16(av[kb], blo, acc8, 0,0,0);
    acc8 = __builtin_amdgcn_mfma_f32_16x16x32_bf16(av[kb], bhi, acc8, 0,0,0);
  }
  // ---- direct full-line xhb stores (no LDS round trip) ----
  #pragma unroll
  for(int m=0;m<4;++m){
    #pragma unroll
    for(int reg=0;reg<4;++reg){
      unsigned pack = (unsigned)f2bf_bits(acc[2*m][reg]) | ((unsigned)f2bf_bits(acc[2*m+1][reg])<<16);
      xhb[(size_t)(r0 + q*4 + reg)*64 + m*16 + r] = pack;
    }
  }
  // ---- asad: LDS transpose to 512B-dense dwordx4 store ----
  if(r < 8){
    #pragma unroll
    for(int reg=0;reg<4;++reg)
      asbuf[wave][(q*4+reg)*8 + r] = acc8[reg];
  }
  // wave-private LDS: compiler lgkmcnt ordering suffices, no barrier.
  if(lane < 32){
    v4f vv = *(const v4f*)&asbuf[wave][lane*4];
    *(v4f*)(asad + (size_t)r0*8 + lane*4) = vv;
  }
}

// half-wave (32 lanes) per node, 8 nodes/block (XCD-chunk swizzled).
// Phase A: parallel softmax anchored at self-logit. Phase B deg<=8: FIXED
// 4x2 unroll exploiting phase A's padding (lds_src=node, lds_coef=0 for
// invalid slots): all 8 row-gathers issue back-to-back -> one latency
// exposure instead of ~3 serial rounds; padded gathers hit the node's own
// row (L1-hot from su). deg 9..16 keeps the loop (~2% of nodes); deg>16
// serial online-softmax.
// asad layout: asad[node*8 + h] = as, asad[node*8 + 4 + h] = ad.
__global__ void k_aggr(const unsigned* __restrict__ xhb, const float* __restrict__ asad,
    const float* __restrict__ ea_csr,
    const float* __restrict__ mebuf,
    const int* __restrict__ rowptr, const int* __restrict__ csr_src,
    const float* __restrict__ bnA_l, const float* __restrict__ bnS_l,
    unsigned* __restrict__ h16, int layer){
  __shared__ float lds_coef[8][16*4];
  __shared__ int   lds_src[8][16];
  int hw = threadIdx.x>>5, lh = threadIdx.x&31;
  int lane = threadIdx.x&63;
  int node = xcd_chunk(blockIdx.x, AGGR_BLOCKS)*8 + hw;
  if(node >= N_NODES) return;
  int s = rowptr[node], e = rowptr[node+1];
  int deg = e - s;
  int hh2 = lh>>3;
  const uint2* xrow = (const uint2*)xhb;
  float a0,a1,a2,a3;

  if(deg <= 16){
    int eidx = lh>>2, h = lh&3;
    int li = layer*4+h;
    float mec0=mebuf[li], mec1=mebuf[16+li], mec2=mebuf[32+li], meb=mebuf[48+li];
    float ad_h = asad[(size_t)node*8+4+h];
    int j0 = eidx;
    float t0 = 0.f, g0 = 0.f;
    int s0 = node;
    bool v0 = (j0 < deg);
    if(v0){
      s0 = csr_src[s+j0];
      v4f qq = ((const v4f*)ea_csr)[s+j0];
      t0 = qq.x*mec0 + qq.y*mec1 + qq.z*mec2;
      g0 = lrelu(asad[(size_t)s0*8+h] + ad_h + t0 + meb);
    }
    float ts, ds, inv;
    if(deg <= 8){
      ts = t0;
      ts += __shfl_xor(ts,4); ts += __shfl_xor(ts,8); ts += __shfl_xor(ts,16);
      float lt = (deg>0) ? ts/(float)deg + meb : 0.f;
      float al = lrelu(asad[(size_t)node*8+h] + ad_h + lt);
      float e0 = v0 ? __expf(g0-al) : 0.f;
      ds = e0;
      ds += __shfl_xor(ds,4); ds += __shfl_xor(ds,8); ds += __shfl_xor(ds,16);
      inv = 1.f/(ds+1.f);
      if(h==0) lds_src[hw][j0] = s0;
      lds_coef[hw][j0*4+h] = e0*inv;
    } else {
      int j1 = 8+eidx;
      float t1 = 0.f, g1 = 0.f;
      int s1 = node;
      bool v1 = (j1 < deg);
      if(v1){
        s1 = csr_src[s+j1];
        v4f qq = ((const v4f*)ea_csr)[s+j1];
        t1 = qq.x*mec0 + qq.y*mec1 + qq.z*mec2;
        g1 = lrelu(asad[(size_t)s1*8+h] + ad_h + t1 + meb);
      }
      ts = t0+t1;
      ts += __shfl_xor(ts,4); ts += __shfl_xor(ts,8); ts += __shfl_xor(ts,16);
      float lt = ts/(float)deg + meb;
      float al = lrelu(asad[(size_t)node*8+h] + ad_h + lt);
      float e0 = v0 ? __expf(g0-al) : 0.f;
      float e1 = v1 ? __expf(g1-al) : 0.f;
      ds = e0+e1;
      ds += __shfl_xor(ds,4); ds += __shfl_xor(ds,8); ds += __shfl_xor(ds,16);
      inv = 1.f/(ds+1.f);
      if(h==0){ lds_src[hw][j0]=s0; lds_src[hw][j1]=s1; }
      lds_coef[hw][j0*4+h] = e0*inv;
      lds_coef[hw][j1*4+h] = e1*inv;
    }
    // ---- phase B ----
    float cs4 = __shfl(inv, (lane&32) | hh2);
    uint2 su = xrow[(size_t)node*32 + lh];
    a0=a1=a2=a3=0.f;
    if(deg <= 8){
      // fixed 4x2 unroll; slots are node/0 padded by phase A
      int sa[4], sb[4];
      #pragma unroll
      for(int u=0;u<4;++u){ sa[u]=lds_src[hw][2*u]; sb[u]=lds_src[hw][2*u+1]; }
      uint2 ua[4], ub[4];
      #pragma unroll
      for(int u=0;u<4;++u){
        ua[u] = xrow[(size_t)sa[u]*32+lh];
        ub[u] = xrow[(size_t)sb[u]*32+lh];
      }
      #pragma unroll
      for(int u=0;u<4;++u){
        float ca = lds_coef[hw][(2*u)*4+hh2];
        float cb = lds_coef[hw][(2*u+1)*4+hh2];
        a0 += ca*bflo(ua[u].x) + cb*bflo(ub[u].x);
        a1 += ca*bfhi(ua[u].x) + cb*bfhi(ub[u].x);
        a2 += ca*bflo(ua[u].y) + cb*bflo(ub[u].y);
        a3 += ca*bfhi(ua[u].y) + cb*bfhi(ub[u].y);
      }
    } else {
      int pdeg = (deg+1)&~1;
      for(int j=0;j<pdeg;j+=2){
        float ca = lds_coef[hw][j*4+hh2];
        float cb = lds_coef[hw][(j+1)*4+hh2];
        int sa = lds_src[hw][j], sb = lds_src[hw][j+1];
        uint2 ua = xrow[(size_t)sa*32+lh];
        uint2 ub = xrow[(size_t)sb*32+lh];
        a0 += ca*bflo(ua.x) + cb*bflo(ub.x);
        a1 += ca*bfhi(ua.x) + cb*bfhi(ub.x);
        a2 += ca*bflo(ua.y) + cb*bflo(ub.y);
        a3 += ca*bfhi(ua.y) + cb*bfhi(ub.y);
      }
    }
    a0 += cs4*bflo(su.x); a1 += cs4*bfhi(su.x);
    a2 += cs4*bflo(su.y); a3 += cs4*bfhi(su.y);
  } else {
    // serial online-softmax path, runs on the half-wave's 32 lanes
    int li = layer*4+hh2;
    float mec0=mebuf[li], mec1=mebuf[16+li], mec2=mebuf[32+li], meb=mebuf[48+li];
    float adv = asad[(size_t)node*8+4+hh2];
    float ts = 0.f;
    for(int j=s;j<e;++j){
      v4f qq = ((const v4f*)ea_csr)[j];
      ts += qq.x*mec0 + qq.y*mec1 + qq.z*mec2;
    }
    float al = lrelu(asad[(size_t)node*8+hh2] + adv + ts/(float)deg + meb);
    float m = al, d = 1.f;
    uint2 su = xrow[(size_t)node*32 + lh];
    float c0=bflo(su.x),c1=bfhi(su.x),c2=bflo(su.y),c3=bfhi(su.y);
    for(int j=s;j<e;++j){
      int sr = csr_src[j];
      v4f qq = ((const v4f*)ea_csr)[j];
      float b = lrelu(asad[(size_t)sr*8+hh2] + adv + qq.x*mec0+qq.y*mec1+qq.z*mec2+meb);
      uint2 uv = xrow[(size_t)sr*32 + lh];
      float nm = fmaxf(m,b);
      float sc = __expf(m-nm), eb = __expf(b-nm);
      d = d*sc + eb;
      c0 = c0*sc + eb*bflo(uv.x); c1 = c1*sc + eb*bfhi(uv.x);
      c2 = c2*sc + eb*bflo(uv.y); c3 = c3*sc + eb*bfhi(uv.y);
      m = nm;
    }
    float inv2 = 1.f/d;
    a0=c0*inv2; a1=c1*inv2; a2=c2*inv2; a3=c3*inv2;
  }

  // epilogue: permuted folded BN + relu + bf16 residual; all 32 lanes active
  {
    const v4f* A4 = (const v4f*)bnA_l;
    const v4f* S4 = (const v4f*)bnS_l;
    v4f A = A4[lh], S = S4[lh];
    uint2 hr = ((const uint2*)h16)[(size_t)node*32 + lh];
    float o0 = fmaxf(a0*A.x+S.x, 0.f) + bflo(hr.x);
    float o1 = fmaxf(a1*A.y+S.y, 0.f) + bfhi(hr.x);
    float o2 = fmaxf(a2*A.z+S.z, 0.f) + bflo(hr.y);
    float o3 = fmaxf(a3*A.w+S.w, 0.f) + bfhi(hr.y);
    uint2 p;
    p.x = (unsigned)f2bf_bits(o0) | ((unsigned)f2bf_bits(o1)<<16);
    p.y = (unsigned)f2bf_bits(o2) | ((unsigned)f2bf_bits(o3)<<16);
    ((uint2*)h16)[(size_t)node*32 + lh] = p;
  }
}

// pooling: one block per graph (XCD-chunk swizzled), 256 threads
// (8 node-slots x 32 uint2 words).
__global__ void k_pool(const unsigned* __restrict__ h16, const int* __restrict__ batch,
                       float* __restrict__ pool){
  __shared__ v4f redA[256];
  __shared__ v4f redB[256];
  __shared__ int sbp[2];
  int t = threadIdx.x;
  int g = xcd_chunk(blockIdx.x, N_GRAPHS);
  if(t < 2){
    int target = g + t;
    int lo=0, hi=N_NODES;
    while(lo<hi){ int mid=(lo+hi)>>1; if(batch[mid] < target) lo=mid+1; else hi=mid; }
    sbp[t]=lo;
  }
  __syncthreads();
  int s = sbp[0], e = sbp[1];
  int w2 = t&31, j8 = t>>5;
  const uint2* xr = (const uint2*)h16;
  float sl0=0.f,sh0=0.f,sl1=0.f,sh1=0.f;
  float ml0=-3.4e38f, mh0=-3.4e38f, ml1=-3.4e38f, mh1=-3.4e38f;
  for(int i=s+j8; i<e; i+=8){
    uint2 v = xr[(size_t)i*32 + w2];
    float a=bflo(v.x), b=bfhi(v.x), c=bflo(v.y), d=bfhi(v.y);
    sl0+=a; sh0+=b; sl1+=c; sh1+=d;
    ml0=fmaxf(ml0,a); mh0=fmaxf(mh0,b); ml1=fmaxf(ml1,c); mh1=fmaxf(mh1,d);
  }
  redA[t] = (v4f){sl0,sh0,sl1,sh1};
  redB[t] = (v4f){ml0,mh0,ml1,mh1};
  __syncthreads();
  if(t < 32){
    v4f S = redA[t], M = redB[t];
    #pragma unroll
    for(int jj=1; jj<8; ++jj){
      v4f a2 = redA[jj*32+t], b2 = redB[jj*32+t];
      S.x+=a2.x; S.y+=a2.y; S.z+=a2.z; S.w+=a2.w;
      M.x=fmaxf(M.x,b2.x); M.y=fmaxf(M.y,b2.y);
      M.z=fmaxf(M.z,b2.z); M.w=fmaxf(M.w,b2.w);
    }
    int cnt = e-s;
    float invc = 1.f/(float)(cnt>1?cnt:1);
    if(cnt==0){ M.x=0.f; M.y=0.f; M.z=0.f; M.w=0.f; }
    // channel map: c00=(w2>>3)*32+(w2&7)*2 ; pairs (c00,c00+1) and (c00+16,c00+17)
    int c00 = (w2>>3)*32 + (w2&7)*2;
    float* pg = pool + (size_t)g*384;
    *(v2f*)&pg[c00]        = (v2f){S.x*invc, S.z*invc};
    *(v2f*)&pg[c00+16]     = (v2f){S.y*invc, S.w*invc};
    *(v2f*)&pg[128+c00]    = (v2f){M.x, M.z};
    *(v2f*)&pg[128+c00+16] = (v2f){M.y, M.w};
    *(v2f*)&pg[256+c00]    = (v2f){S.x, S.z};
    *(v2f*)&pg[256+c00+16] = (v2f){S.y, S.w};
  }
}

// head MLP: 4 graphs/block, 512 blocks (2 blocks/CU, 8 waves/CU).
// Pooled tile staged in LDS poolT[k][4] (v4f broadcast reads). Each stage's
// k-loop manually unrolled x4 with batched weight loads (>=4 loads in flight).
__global__ void k_head(const float* __restrict__ pool,
   const float* __restrict__ gf,
   const float* __restrict__ gc_w, const float* __restrict__ gc_b,
   const float* __restrict__ gf1_w, const float* __restrict__ gf1_b,
   const float* __restrict__ gf2_w, const float* __restrict__ gf2_b,
   const float* __restrict__ p1_w, const float* __restrict__ p1_b,
   const float* __restrict__ p2_w, const float* __restrict__ p2_b,
   const float* __restrict__ p3_w, const float* __restrict__ p3_b,
   float* __restrict__ out){
  __shared__ float poolT[384*4];   // [k][g]
  __shared__ float hid1s[64*4];
  __shared__ float partial[128*4]; // v4f per c
  __shared__ float combT[192*4];
  __shared__ float r1T[128*4];
  __shared__ float ppb[3*64*4];
  __shared__ float r2T[64*4];
  int t = threadIdx.x;
  int g0 = blockIdx.x*4;

  // stage pooled tile: poolT[k*4+g] = pool[(g0+g)*384+k]
  for(int idx=t; idx<1536; idx+=256)
    poolT[idx] = pool[(size_t)(g0+(idx&3))*384 + (idx>>2)];
  // glob hid1 (no dep on poolT)
  {
    int c=t&63, g=t>>6;
    float a = gf1_b[c];
    #pragma unroll
    for(int i=0;i<10;++i) a += gf[(size_t)(g0+g)*10+i]*gf1_w[i*64+c];
    hid1s[c*4+g] = fmaxf(a,0.f);
  }
  __syncthreads();

  int c = t&127, half = t>>7;
  const v4f* poolv = (const v4f*)poolT;
  const v4f* combv = (const v4f*)combT;
  const v4f* r1v = (const v4f*)r1T;

  // ---- gc: 384-k split in 2 halves of 192, unroll 4 ----
  v4f acc = {0.f,0.f,0.f,0.f};
  {
    int kb = half*192;
    for(int kk=0; kk<192; kk+=4){
      int k = kb+kk;
      float w0 = gc_w[(k+0)*128+c];
      float w1 = gc_w[(k+1)*128+c];
      float w2 = gc_w[(k+2)*128+c];
      float w3 = gc_w[(k+3)*128+c];
      v4f p0=poolv[k+0], p1=poolv[k+1], p2=poolv[k+2], p3=poolv[k+3];
      acc += p0*w0; acc += p1*w1; acc += p2*w2; acc += p3*w3;
    }
  }
  // gf2 -> combT[128..191]
  {
    int cc=t&63, g=t>>6;
    float a = gf2_b[cc];
    #pragma unroll 4
    for(int k=0;k<64;++k) a += hid1s[k*4+g]*gf2_w[k*64+cc];
    combT[(128+cc)*4+g] = a;
  }
  if(half==1) *(v4f*)&partial[c*4] = acc;
  __syncthreads();
  if(half==0){
    v4f pb = *(const v4f*)&partial[c*4];
    float bias = gc_b[c];
    v4f r;
    r.x = fmaxf(acc.x+pb.x+bias, 0.f);
    r.y = fmaxf(acc.y+pb.y+bias, 0.f);
    r.z = fmaxf(acc.z+pb.z+bias, 0.f);
    r.w = fmaxf(acc.w+pb.w+bias, 0.f);
    *(v4f*)&combT[c*4] = r;
  }
  __syncthreads();

  // ---- p1: 192-k split in 2 halves of 96, unroll 4 ----
  v4f a1 = {0.f,0.f,0.f,0.f};
  {
    int kb = half*96;
    for(int kk=0; kk<96; kk+=4){
      int k = kb+kk;
      float w0 = p1_w[(k+0)*128+c];
      float w1 = p1_w[(k+1)*128+c];
      float w2 = p1_w[(k+2)*128+c];
      float w3 = p1_w[(k+3)*128+c];
      v4f p0=combv[k+0], p1=combv[k+1], p2=combv[k+2], p3=combv[k+3];
      a1 += p0*w0; a1 += p1*w1; a1 += p2*w2; a1 += p3*w3;
    }
  }
  if(half==1) *(v4f*)&partial[c*4] = a1;
  __syncthreads();
  if(half==0){
    v4f pb = *(const v4f*)&partial[c*4];
    float b1 = p1_b[c];
    v4f r;
    r.x = fmaxf(a1.x+pb.x+b1, 0.f);
    r.y = fmaxf(a1.y+pb.y+b1, 0.f);
    r.z = fmaxf(a1.z+pb.z+b1, 0.f);
    r.w = fmaxf(a1.w+pb.w+b1, 0.f);
    *(v4f*)&r1T[c*4] = r;
  }
  __syncthreads();

  // ---- p2: 128-k split in 4 quarters of 32, unroll 4 ----
  {
    int c2=t&63, qd=t>>6;
    v4f a2 = {0.f,0.f,0.f,0.f};
    int kb = qd*32;
    for(int kk=0; kk<32; kk+=4){
      int k = kb+kk;
      float w0 = p2_w[(k+0)*64+c2];
      float w1 = p2_w[(k+1)*64+c2];
      float w2 = p2_w[(k+2)*64+c2];
      float w3 = p2_w[(k+3)*64+c2];
      v4f p0=r1v[k+0], p1=r1v[k+1], p2=r1v[k+2], p3=r1v[k+3];
      a2 += p0*w0; a2 += p1*w1; a2 += p2*w2; a2 += p3*w3;
    }
    if(qd>0) *(v4f*)&ppb[((qd-1)*64+c2)*4] = a2;
    __syncthreads();
    if(qd==0){
      v4f q1 = *(const v4f*)&ppb[(0*64+c2)*4];
      v4f q2 = *(const v4f*)&ppb[(1*64+c2)*4];
      v4f q3 = *(const v4f*)&ppb[(2*64+c2)*4];
      float b2 = p2_b[c2];
      v4f r;
      r.x = fmaxf(a2.x+q1.x+q2.x+q3.x+b2, 0.f);
      r.y = fmaxf(a2.y+q1.y+q2.y+q3.y+b2, 0.f);
      r.z = fmaxf(a2.z+q1.z+q2.z+q3.z+b2, 0.f);
      r.w = fmaxf(a2.w+q1.w+q2.w+q3.w+b2, 0.f);
      *(v4f*)&r2T[c2*4] = r;
    }
    __syncthreads();
  }

  // ---- p3 ----
  if(t < 20){
    int g = t/5, o = t%5;
    float a = p3_b[o];
    #pragma unroll 4
    for(int k=0;k<64;++k) a += r2T[k*4+g]*p3_w[k*TOUT+o];
    out[(size_t)(g0+g)*TOUT+o] = a;
  }
}

extern "C" void kernel_launch(void* const* d_in, const int* in_sizes, int n_in,
                              void* d_out, int out_size, void* d_ws, size_t ws_size,
                              hipStream_t stream){
  (void)in_sizes; (void)n_in; (void)out_size; (void)ws_size;
  const float* x        = (const float*)d_in[0];
  const int*   ei       = (const int*)d_in[1];
  const float* ea       = (const float*)d_in[2];
  const int*   batch    = (const int*)d_in[3];
  const float* gfin     = (const float*)d_in[4];
  const float* node_w   = (const float*)d_in[5];
  const float* node_b   = (const float*)d_in[6];
  const float* edge_w   = (const float*)d_in[7];
  const float* edge_b   = (const float*)d_in[8];
  const float* gat_lin_w  = (const float*)d_in[9];
  const float* gat_edge_w = (const float*)d_in[10];
  const float* att_src  = (const float*)d_in[11];
  const float* att_dst  = (const float*)d_in[12];
  const float* att_edge = (const float*)d_in[13];
  const float* gat_bias = (const float*)d_in[14];
  const float* bn_gamma = (const float*)d_in[15];
  const float* bn_beta  = (const float*)d_in[16];
  const float* bn_mean  = (const float*)d_in[17];
  const float* bn_var   = (const float*)d_in[18];
  const float* gc_w = (const float*)d_in[19];
  const float* gc_b = (const float*)d_in[20];
  const float* gf1_w = (const float*)d_in[21];
  const float* gf1_b = (const float*)d_in[22];
  const float* gf2_w = (const float*)d_in[23];
  const float* gf2_b = (const float*)d_in[24];
  const float* p1_w = (const float*)d_in[25];
  const float* p1_b = (const float*)d_in[26];
  const float* p2_w = (const float*)d_in[27];
  const float* p2_b = (const float*)d_in[28];
  const float* p3_w = (const float*)d_in[29];
  const float* p3_b = (const float*)d_in[30];
  float* out = (float*)d_out;

  char* w = (char*)d_ws;
  size_t o = 0;
  auto carve = [&](size_t bytes)->char*{
    char* p = w + o; o += (bytes + 255) & ~(size_t)255; return p;
  };
  unsigned* xhb = (unsigned*)carve((size_t)N_NODES*64*4);
  unsigned* h16 = (unsigned*)carve((size_t)N_NODES*64*4);
  float* ea_csr = (float*)carve((size_t)N_EDGES*4*4);
  float* asad   = (float*)carve((size_t)N_NODES*8*4);
  int* deg      = (int*)carve((size_t)N_NODES*4);
  int* rowptr   = (int*)carve((size_t)(N_NODES+1)*4);
  int* fill     = (int*)carve((size_t)N_NODES*4);
  int* csr_src  = (int*)carve((size_t)N_EDGES*4);
  int* part     = (int*)carve(1024*4);
  float* mebuf  = (float*)carve(64*4);
  float* bnA    = (float*)carve((size_t)NLAYER*HID*4);
  float* bnS    = (float*)carve((size_t)NLAYER*HID*4);
  unsigned short* whi = (unsigned short*)carve(65536*2);
  unsigned short* whiE = (unsigned short*)carve(8192*2);
  unsigned short* wloE = (unsigned short*)carve(8192*2);
  float* pool   = (float*)carve((size_t)N_GRAPHS*384*4);

  // setup: mebuf + BNfold + w_ext + wswz + zero(deg,fill) + hinit
  k_setup<<<1688 + HINIT_BLOCKS, 256, 0, stream>>>(gat_edge_w, att_edge, edge_w, edge_b,
        gat_bias, bn_gamma, bn_beta, bn_mean, bn_var,
        gat_lin_w, att_src, att_dst, x, node_w, node_b, h16,
        mebuf, bnA, bnS, whiE, wloE, whi, deg, fill);
  k_deg<<<(N_EDGES+255)/256, 256, 0, stream>>>(ei, deg);
  k_scan1<<<NB,256,0,stream>>>(deg, part);
  k_scan3<<<NB,256,0,stream>>>(deg, part, rowptr);

  for(int l=0;l<NLAYER;++l){
    int gb = (l==0) ? GEMM_BLOCKS + (N_EDGES+255)/256 : GEMM_BLOCKS;
    k_gemm<<<gb,256,0,stream>>>((const unsigned short*)h16,
        whi + l*16384, whiE + l*2048, wloE + l*2048,
        xhb, asad, ei, ea, rowptr, fill, csr_src, ea_csr);
    k_aggr<<<AGGR_BLOCKS,256,0,stream>>>(xhb, asad, ea_csr, mebuf,
        rowptr, csr_src, bnA + l*128, bnS + l*128, h16, l);
  }

  k_pool<<<N_GRAPHS,256,0,stream>>>(h16, batch, pool);
  k_head<<<N_GRAPHS/4,256,0,stream>>>(pool, gfin, gc_w, gc_b, gf1_w, gf1_b,
        gf2_w, gf2_b, p1_w, p1_b, p2_w, p2_b, p3_w, p3_b, out);
}

// Round 11
// 418.590 us; speedup vs baseline: 1.0225x; 1.0225x over previous
//
#include <hip/hip_runtime.h>

#define N_NODES 100000
#define N_EDGES 400000
#define N_GRAPHS 2048
#define HID 128
#define NLAYER 4
#define TOUT 5
#define EPSV 1e-5f
#define SLOPE 0.2f
#define NB 98   // (N_NODES+1023)/1024
#define GEMM_BLOCKS 1563  // ceil(N_NODES/64)
#define AGGR_BLOCKS 12500 // N_NODES/8
#define HINIT_BLOCKS 25000 // N_NODES/4

typedef float v4f __attribute__((ext_vector_type(4)));
typedef float v2f __attribute__((ext_vector_type(2)));
typedef __bf16 v8bf __attribute__((ext_vector_type(8)));

static __device__ __forceinline__ unsigned short f2bf_bits(float f){
  unsigned u = __builtin_bit_cast(unsigned, f);
  unsigned r = u + 0x7fffu + ((u >> 16) & 1u);
  return (unsigned short)(r >> 16);
}
static __device__ __forceinline__ float bfbits2f(unsigned short s){
  unsigned u = ((unsigned)s) << 16;
  return __builtin_bit_cast(float, u);
}
static __device__ __forceinline__ float bflo(unsigned u){
  return __builtin_bit_cast(float, u << 16);
}
static __device__ __forceinline__ float bfhi(unsigned u){
  return __builtin_bit_cast(float, u & 0xffff0000u);
}
static __device__ __forceinline__ float lrelu(float v){
  return v>0.f ? v : SLOPE*v;
}

// Bijective XCD-chunk swizzle (m204). Kept: null-but-harmless.
static __device__ __forceinline__ int xcd_chunk(int bid, int nwg){
  int q = nwg >> 3, r = nwg & 7;
  int x = bid & 7, i = bid >> 3;
  return (x < r ? x*(q+1) : r*(q+1) + (x - r)*q) + i;
}

// Physical bf16 layout (head-aligned pairing):
//   word u (0..63): b=u>>4, r=u&15 -> holds channels (b*32+r [lo], b*32+16+r [hi]).
//   Lane l (words 2l,2l+1) is entirely head l>>3.
//   contraction position for channel k: kp = (k>>5)*32 + (k&15)*2 + ((k>>4)&1).

// merged setup:
//  blocks 0..15      : mebuf direct (wave-per-output, parallel)
//  block  16         : BN fold
//  blocks 17..1040   : w_ext (split hi/lo)
//  blocks 1041..1296 : wswz (single bf16 W)
//  blocks 1297..1687 : zero deg/fill
//  blocks 1688..     : hinit (XCD-chunk swizzled)
__global__ void k_setup(const float* __restrict__ gat_edge_w, const float* __restrict__ att_edge,
                        const float* __restrict__ edge_w, const float* __restrict__ edge_b,
                        const float* __restrict__ gat_bias, const float* __restrict__ gamma,
                        const float* __restrict__ beta, const float* __restrict__ mean,
                        const float* __restrict__ var, const float* __restrict__ gat_lin_w,
                        const float* __restrict__ att_src, const float* __restrict__ att_dst,
                        const float* __restrict__ x, const float* __restrict__ nw,
                        const float* __restrict__ nb, unsigned* __restrict__ h16,
                        float* __restrict__ mebuf, float* __restrict__ bnA, float* __restrict__ bnS,
                        unsigned short* __restrict__ whiE, unsigned short* __restrict__ wloE,
                        unsigned short* __restrict__ whi,
                        int* __restrict__ deg, int* __restrict__ fill){
  int bid = blockIdx.x, t = threadIdx.x;
  if(bid < 16){
    // mebuf[o], o = bid*4 + wave; o<48: edge_w row f=o>>4; o>=48: edge_b
    int wv = t>>6, lane = t&63;
    int o = bid*4 + wv;
    int li = (o<48)? (o&15) : (o-48);
    int f = o>>4;
    int l = li>>2, hh = li&3;
    int c = lane&31, kk = lane>>5;
    float at_c = att_edge[l*128 + hh*32 + c];
    float acc = 0.f;
    #pragma unroll 8
    for(int t2=0; t2<64; ++t2){
      int k = kk*64 + t2;
      float wk = (o<48)? edge_w[f*128+k] : edge_b[k];
      acc += wk * gat_edge_w[l*16384 + k*128 + hh*32 + c];
    }
    acc *= at_c;
    acc += __shfl_xor(acc,1); acc += __shfl_xor(acc,2); acc += __shfl_xor(acc,4);
    acc += __shfl_xor(acc,8); acc += __shfl_xor(acc,16); acc += __shfl_xor(acc,32);
    if(lane==0) mebuf[o] = acc;
  } else if(bid == 16){
    for(int i=t; i<NLAYER*HID; i+=256){
      int l_ = i>>7, pos = i&127, lane = pos>>2, j = pos&3;
      int ch = ((lane>>3)<<5) + ((lane&7)<<1) + ((j&1)<<4) + (j>>1);
      int src = l_*128 + ch;
      float A = gamma[src]*rsqrtf(var[src]+EPSV);
      bnA[i] = A;
      bnS[i] = (gat_bias[src]-mean[src])*A + beta[src];
    }
  } else if(bid <= 1040){
    int wave = t>>6, lane = t&63;
    int i = (bid-17)*8 + wave*2 + (lane>>5);   // 0..8191
    int l_ = i>>11, rest = i&2047, kp = rest>>4, col = rest&15;
    int sub = lane&31;
    float val = 0.f;
    if(col < 8){
      int h_ = col&3, isdst = col>>2;
      int ch = ((kp>>5)<<5) + ((kp&1)<<4) + ((kp&31)>>1);
      const float* at = (isdst? att_dst : att_src);
      val = gat_lin_w[l_*16384 + ch*128 + h_*32 + sub] * at[l_*128 + h_*32 + sub];
    }
    val += __shfl_xor(val,1); val += __shfl_xor(val,2); val += __shfl_xor(val,4);
    val += __shfl_xor(val,8); val += __shfl_xor(val,16);
    if(sub == 0){
      unsigned short hi = f2bf_bits(val);
      unsigned short lo = f2bf_bits(val - bfbits2f(hi));
      int kb=kp>>5, quad=(kp>>3)&3, jj=kp&7, lane2=quad*16+col;
      int dst = ((l_*4+kb)*64 + lane2)*8 + jj;
      whiE[dst]=hi; wloE[dst]=lo;
    }
  } else if(bid <= 1296){
    int tg = (bid-1041)*256 + t;              // 0..65535 == dst index
    int base = tg>>9, off = tg&511;
    int l = base>>5, kb=(base>>3)&3, cg=base&7;
    int lane = off>>3, j = off&7;
    int quad = lane>>4, r = lane&15;
    int kp = kb*32 + quad*8 + j;
    int k = ((kp>>5)<<5) | ((kp&1)<<4) | ((kp&31)>>1);
    whi[tg] = f2bf_bits(gat_lin_w[l*16384 + k*128 + cg*16 + r]);
  } else if(bid <= 1687){
    int tg = (bid-1297)*256 + t;
    if(tg < N_NODES){ deg[tg]=0; fill[tg]=0; }
  } else {
    int j = bid - 1688;
    int node = xcd_chunk(j, HINIT_BLOCKS)*4 + (t>>6);
    int c = t&63;
    int ch = ((c>>4)<<5) + (c&15);
    float a0 = nb[ch], a1 = nb[ch+16];
    #pragma unroll
    for(int f=0; f<7; ++f){
      float xv = x[node*7+f];
      a0 += xv*nw[f*HID+ch];
      a1 += xv*nw[f*HID+ch+16];
    }
    unsigned p = (unsigned)f2bf_bits(a0) | ((unsigned)f2bf_bits(a1)<<16);
    h16[(size_t)node*64 + c] = p;
  }
}

// deg count only (after zeroing in k_setup)
__global__ void k_deg(const int* __restrict__ ei, int* __restrict__ deg){
  int e = blockIdx.x*256 + threadIdx.x;
  if(e < N_EDGES) atomicAdd(&deg[ei[N_EDGES+e]], 1);
}

// scan phase 1: per-chunk sums
__global__ void k_scan1(const int* __restrict__ deg, int* __restrict__ part){
  __shared__ int s[256];
  int t=threadIdx.x; int base = blockIdx.x*1024 + t*4;
  int sum=0;
  #pragma unroll
  for(int j=0;j<4;++j){ int i=base+j; sum += (i<N_NODES)? deg[i]:0; }
  s[t]=sum; __syncthreads();
  for(int off=128; off>0; off>>=1){ if(t<off) s[t]+=s[t+off]; __syncthreads(); }
  if(t==0) part[blockIdx.x]=s[0];
}
// scan phase 2+3 fused
__global__ void k_scan3(const int* __restrict__ deg, const int* __restrict__ part,
                        int* __restrict__ rowptr){
  __shared__ int s[256];
  int t=threadIdx.x, b=blockIdx.x;
  int g = 0, tot = 0;
  for(int i=0;i<NB;++i){ int v = part[i]; g += (i<b)? v : 0; tot += v; }
  if(b==0 && t==0) rowptr[N_NODES]=tot;
  int base = b*1024 + t*4;
  int v[4]; int sum=0; int pre[4];
  #pragma unroll
  for(int j=0;j<4;++j){ int i=base+j; v[j]=(i<N_NODES)?deg[i]:0; pre[j]=sum; sum+=v[j]; }
  s[t]=sum; __syncthreads();
  for(int off=1; off<256; off<<=1){
    int xv = (t>=off)? s[t-off]:0; __syncthreads();
    s[t]+=xv; __syncthreads();
  }
  int toff = (t>0)? s[t-1]:0;
  #pragma unroll
  for(int j=0;j<4;++j){ int i=base+j; if(i<N_NODES) rowptr[i]=g+toff+pre[j]; }
}

// xh = h16 @ W[l]. 64 rows/block, one 16-row tile per wave. Weights (40KB)
// staged into LDS once per block; MFMA reads via ds_read_b128. LDS-free xhb
// epilogue (full-line stores); asad via 512B wave-private LDS transpose.
// Layer-0 launch carries CSR-build tail blocks.
__global__ void k_gemm(const unsigned short* __restrict__ h16,
                       const unsigned short* __restrict__ whi,
                       const unsigned short* __restrict__ whiE,
                       const unsigned short* __restrict__ wloE,
                       unsigned* __restrict__ xhb, float* __restrict__ asad,
                       const int* __restrict__ ei, const float* __restrict__ ea,
                       const int* __restrict__ rowptr, int* __restrict__ fill,
                       int* __restrict__ csr_src, float* __restrict__ ea_csr){
  if(blockIdx.x >= GEMM_BLOCKS){
    int e = (blockIdx.x - GEMM_BLOCKS)*256 + threadIdx.x;
    if(e < N_EDGES){
      int dst = ei[N_EDGES+e];
      int pos = rowptr[dst] + atomicAdd(&fill[dst],1);
      csr_src[pos] = ei[e];
      v4f q = {ea[e*3], ea[e*3+1], ea[e*3+2], 0.f};
      ((v4f*)ea_csr)[pos] = q;
    }
    return;
  }
  __shared__ uint4 whi_s4[2048];   // 32KB
  __shared__ uint4 wE_s4[256];     // 4KB
  __shared__ uint4 wL_s4[256];     // 4KB
  __shared__ float asbuf[4][128];
  int t = threadIdx.x;
  int wave = t>>6, lane = t&63;
  int q = lane>>4, r = lane&15;
  int wb = xcd_chunk(blockIdx.x, GEMM_BLOCKS);
  int r0 = wb*64 + wave*16;
  if(r0 > N_NODES-16) r0 = N_NODES-16;

  // ---- cooperative weight staging (coalesced, fully pipelined) ----
  {
    const uint4* s4 = (const uint4*)whi;
    #pragma unroll
    for(int i=0;i<8;++i) whi_s4[i*256+t] = s4[i*256+t];
    wE_s4[t] = ((const uint4*)whiE)[t];
    wL_s4[t] = ((const uint4*)wloE)[t];
  }

  v8bf av[4];
  {
    const unsigned short* hrow = h16 + (size_t)(r0 + r)*HID;
    #pragma unroll
    for(int kb=0;kb<4;++kb)
      av[kb] = *(const v8bf*)(hrow + kb*32 + q*8);
  }
  __syncthreads();

  const unsigned short* whi_s = (const unsigned short*)whi_s4;
  const unsigned short* whiE_s = (const unsigned short*)wE_s4;
  const unsigned short* wloE_s = (const unsigned short*)wL_s4;

  v4f acc[8];
  #pragma unroll
  for(int cg=0;cg<8;++cg){
    v4f a0 = {0.f,0.f,0.f,0.f};
    #pragma unroll
    for(int kb=0;kb<4;++kb){
      v8bf bhi = *(const v8bf*)(whi_s + ((kb*8+cg)*64 + lane)*8);
      a0 = __builtin_amdgcn_mfma_f32_16x16x32_bf16(av[kb], bhi, a0, 0,0,0);
    }
    acc[cg]=a0;
  }
  v4f acc8 = {0.f,0.f,0.f,0.f};
  #pragma unroll
  for(int kb=0;kb<4;++kb){
    v8bf bhi = *(const v8bf*)(whiE_s + (kb*64 + lane)*8);
    v8bf blo = *(const v8bf*)(wloE_s + (kb*64 + lane)*8);
    acc8 = __builtin_amdgcn_mfma_f32_16x16x32_bf16(av[kb], blo, acc8, 0,0,0);
    acc8 = __builtin_amdgcn_mfma_f32_16x16x32_bf16(av[kb], bhi, acc8, 0,0,0);
  }
  // ---- direct full-line xhb stores (no LDS round trip) ----
  #pragma unroll
  for(int m=0;m<4;++m){
    #pragma unroll
    for(int reg=0;reg<4;++reg){
      unsigned pack = (unsigned)f2bf_bits(acc[2*m][reg]) | ((unsigned)f2bf_bits(acc[2*m+1][reg])<<16);
      xhb[(size_t)(r0 + q*4 + reg)*64 + m*16 + r] = pack;
    }
  }
  // ---- asad: LDS transpose to 512B-dense dwordx4 store ----
  if(r < 8){
    #pragma unroll
    for(int reg=0;reg<4;++reg)
      asbuf[wave][(q*4+reg)*8 + r] = acc8[reg];
  }
  // wave-private LDS: compiler lgkmcnt ordering suffices, no barrier.
  if(lane < 32){
    v4f vv = *(const v4f*)&asbuf[wave][lane*4];
    *(v4f*)(asad + (size_t)r0*8 + lane*4) = vv;
  }
}

// half-wave (32 lanes) per node, 8 nodes/block (XCD-chunk swizzled).
// Phase A: parallel softmax anchored at self-logit; deg<=8 fast path,
// deg<=16 two-round, serial online-softmax deg>16. Phase B: loop form
// (R9 variant — measured best; R10's fixed unroll regressed).
// asad layout: asad[node*8 + h] = as, asad[node*8 + 4 + h] = ad.
__global__ void k_aggr(const unsigned* __restrict__ xhb, const float* __restrict__ asad,
    const float* __restrict__ ea_csr,
    const float* __restrict__ mebuf,
    const int* __restrict__ rowptr, const int* __restrict__ csr_src,
    const float* __restrict__ bnA_l, const float* __restrict__ bnS_l,
    unsigned* __restrict__ h16, int layer){
  __shared__ float lds_coef[8][16*4];
  __shared__ int   lds_src[8][16];
  int hw = threadIdx.x>>5, lh = threadIdx.x&31;
  int lane = threadIdx.x&63;
  int node = xcd_chunk(blockIdx.x, AGGR_BLOCKS)*8 + hw;
  if(node >= N_NODES) return;
  int s = rowptr[node], e = rowptr[node+1];
  int deg = e - s;
  int hh2 = lh>>3;
  const uint2* xrow = (const uint2*)xhb;
  float a0,a1,a2,a3;

  if(deg <= 16){
    int eidx = lh>>2, h = lh&3;
    int li = layer*4+h;
    float mec0=mebuf[li], mec1=mebuf[16+li], mec2=mebuf[32+li], meb=mebuf[48+li];
    float ad_h = asad[(size_t)node*8+4+h];
    int j0 = eidx;
    float t0 = 0.f, g0 = 0.f;
    int s0 = node;
    bool v0 = (j0 < deg);
    if(v0){
      s0 = csr_src[s+j0];
      v4f qq = ((const v4f*)ea_csr)[s+j0];
      t0 = qq.x*mec0 + qq.y*mec1 + qq.z*mec2;
      g0 = lrelu(asad[(size_t)s0*8+h] + ad_h + t0 + meb);
    }
    float ts, ds, inv;
    if(deg <= 8){
      ts = t0;
      ts += __shfl_xor(ts,4); ts += __shfl_xor(ts,8); ts += __shfl_xor(ts,16);
      float lt = (deg>0) ? ts/(float)deg + meb : 0.f;
      float al = lrelu(asad[(size_t)node*8+h] + ad_h + lt);
      float e0 = v0 ? __expf(g0-al) : 0.f;
      ds = e0;
      ds += __shfl_xor(ds,4); ds += __shfl_xor(ds,8); ds += __shfl_xor(ds,16);
      inv = 1.f/(ds+1.f);
      if(h==0) lds_src[hw][j0] = s0;
      lds_coef[hw][j0*4+h] = e0*inv;
    } else {
      int j1 = 8+eidx;
      float t1 = 0.f, g1 = 0.f;
      int s1 = node;
      bool v1 = (j1 < deg);
      if(v1){
        s1 = csr_src[s+j1];
        v4f qq = ((const v4f*)ea_csr)[s+j1];
        t1 = qq.x*mec0 + qq.y*mec1 + qq.z*mec2;
        g1 = lrelu(asad[(size_t)s1*8+h] + ad_h + t1 + meb);
      }
      ts = t0+t1;
      ts += __shfl_xor(ts,4); ts += __shfl_xor(ts,8); ts += __shfl_xor(ts,16);
      float lt = ts/(float)deg + meb;
      float al = lrelu(asad[(size_t)node*8+h] + ad_h + lt);
      float e0 = v0 ? __expf(g0-al) : 0.f;
      float e1 = v1 ? __expf(g1-al) : 0.f;
      ds = e0+e1;
      ds += __shfl_xor(ds,4); ds += __shfl_xor(ds,8); ds += __shfl_xor(ds,16);
      inv = 1.f/(ds+1.f);
      if(h==0){ lds_src[hw][j0]=s0; lds_src[hw][j1]=s1; }
      lds_coef[hw][j0*4+h] = e0*inv;
      lds_coef[hw][j1*4+h] = e1*inv;
    }
    // ---- phase B ----
    float cs4 = __shfl(inv, (lane&32) | hh2);
    uint2 su = xrow[(size_t)node*32 + lh];
    int pdeg = (deg+1)&~1;
    a0=a1=a2=a3=0.f;
    for(int j=0;j<pdeg;j+=2){
      float ca = lds_coef[hw][j*4+hh2];
      float cb = lds_coef[hw][(j+1)*4+hh2];
      int sa = lds_src[hw][j], sb = lds_src[hw][j+1];
      uint2 ua = xrow[(size_t)sa*32+lh];
      uint2 ub = xrow[(size_t)sb*32+lh];
      a0 += ca*bflo(ua.x) + cb*bflo(ub.x);
      a1 += ca*bfhi(ua.x) + cb*bfhi(ub.x);
      a2 += ca*bflo(ua.y) + cb*bflo(ub.y);
      a3 += ca*bfhi(ua.y) + cb*bfhi(ub.y);
    }
    a0 += cs4*bflo(su.x); a1 += cs4*bfhi(su.x);
    a2 += cs4*bflo(su.y); a3 += cs4*bfhi(su.y);
  } else {
    // serial online-softmax path, runs on the half-wave's 32 lanes
    int li = layer*4+hh2;
    float mec0=mebuf[li], mec1=mebuf[16+li], mec2=mebuf[32+li], meb=mebuf[48+li];
    float adv = asad[(size_t)node*8+4+hh2];
    float ts = 0.f;
    for(int j=s;j<e;++j){
      v4f qq = ((const v4f*)ea_csr)[j];
      ts += qq.x*mec0 + qq.y*mec1 + qq.z*mec2;
    }
    float al = lrelu(asad[(size_t)node*8+hh2] + adv + ts/(float)deg + meb);
    float m = al, d = 1.f;
    uint2 su = xrow[(size_t)node*32 + lh];
    float c0=bflo(su.x),c1=bfhi(su.x),c2=bflo(su.y),c3=bfhi(su.y);
    for(int j=s;j<e;++j){
      int sr = csr_src[j];
      v4f qq = ((const v4f*)ea_csr)[j];
      float b = lrelu(asad[(size_t)sr*8+hh2] + adv + qq.x*mec0+qq.y*mec1+qq.z*mec2+meb);
      uint2 uv = xrow[(size_t)sr*32 + lh];
      float nm = fmaxf(m,b);
      float sc = __expf(m-nm), eb = __expf(b-nm);
      d = d*sc + eb;
      c0 = c0*sc + eb*bflo(uv.x); c1 = c1*sc + eb*bfhi(uv.x);
      c2 = c2*sc + eb*bflo(uv.y); c3 = c3*sc + eb*bfhi(uv.y);
      m = nm;
    }
    float inv2 = 1.f/d;
    a0=c0*inv2; a1=c1*inv2; a2=c2*inv2; a3=c3*inv2;
  }

  // epilogue: permuted folded BN + relu + bf16 residual; all 32 lanes active
  {
    const v4f* A4 = (const v4f*)bnA_l;
    const v4f* S4 = (const v4f*)bnS_l;
    v4f A = A4[lh], S = S4[lh];
    uint2 hr = ((const uint2*)h16)[(size_t)node*32 + lh];
    float o0 = fmaxf(a0*A.x+S.x, 0.f) + bflo(hr.x);
    float o1 = fmaxf(a1*A.y+S.y, 0.f) + bfhi(hr.x);
    float o2 = fmaxf(a2*A.z+S.z, 0.f) + bflo(hr.y);
    float o3 = fmaxf(a3*A.w+S.w, 0.f) + bfhi(hr.y);
    uint2 p;
    p.x = (unsigned)f2bf_bits(o0) | ((unsigned)f2bf_bits(o1)<<16);
    p.y = (unsigned)f2bf_bits(o2) | ((unsigned)f2bf_bits(o3)<<16);
    ((uint2*)h16)[(size_t)node*32 + lh] = p;
  }
}

// pooling: one block per graph (XCD-chunk swizzled), 256 threads
// (8 node-slots x 32 uint2 words).
__global__ void k_pool(const unsigned* __restrict__ h16, const int* __restrict__ batch,
                       float* __restrict__ pool){
  __shared__ v4f redA[256];
  __shared__ v4f redB[256];
  __shared__ int sbp[2];
  int t = threadIdx.x;
  int g = xcd_chunk(blockIdx.x, N_GRAPHS);
  if(t < 2){
    int target = g + t;
    int lo=0, hi=N_NODES;
    while(lo<hi){ int mid=(lo+hi)>>1; if(batch[mid] < target) lo=mid+1; else hi=mid; }
    sbp[t]=lo;
  }
  __syncthreads();
  int s = sbp[0], e = sbp[1];
  int w2 = t&31, j8 = t>>5;
  const uint2* xr = (const uint2*)h16;
  float sl0=0.f,sh0=0.f,sl1=0.f,sh1=0.f;
  float ml0=-3.4e38f, mh0=-3.4e38f, ml1=-3.4e38f, mh1=-3.4e38f;
  for(int i=s+j8; i<e; i+=8){
    uint2 v = xr[(size_t)i*32 + w2];
    float a=bflo(v.x), b=bfhi(v.x), c=bflo(v.y), d=bfhi(v.y);
    sl0+=a; sh0+=b; sl1+=c; sh1+=d;
    ml0=fmaxf(ml0,a); mh0=fmaxf(mh0,b); ml1=fmaxf(ml1,c); mh1=fmaxf(mh1,d);
  }
  redA[t] = (v4f){sl0,sh0,sl1,sh1};
  redB[t] = (v4f){ml0,mh0,ml1,mh1};
  __syncthreads();
  if(t < 32){
    v4f S = redA[t], M = redB[t];
    #pragma unroll
    for(int jj=1; jj<8; ++jj){
      v4f a2 = redA[jj*32+t], b2 = redB[jj*32+t];
      S.x+=a2.x; S.y+=a2.y; S.z+=a2.z; S.w+=a2.w;
      M.x=fmaxf(M.x,b2.x); M.y=fmaxf(M.y,b2.y);
      M.z=fmaxf(M.z,b2.z); M.w=fmaxf(M.w,b2.w);
    }
    int cnt = e-s;
    float invc = 1.f/(float)(cnt>1?cnt:1);
    if(cnt==0){ M.x=0.f; M.y=0.f; M.z=0.f; M.w=0.f; }
    // channel map: c00=(w2>>3)*32+(w2&7)*2 ; pairs (c00,c00+1) and (c00+16,c00+17)
    int c00 = (w2>>3)*32 + (w2&7)*2;
    float* pg = pool + (size_t)g*384;
    *(v2f*)&pg[c00]        = (v2f){S.x*invc, S.z*invc};
    *(v2f*)&pg[c00+16]     = (v2f){S.y*invc, S.w*invc};
    *(v2f*)&pg[128+c00]    = (v2f){M.x, M.z};
    *(v2f*)&pg[128+c00+16] = (v2f){M.y, M.w};
    *(v2f*)&pg[256+c00]    = (v2f){S.x, S.z};
    *(v2f*)&pg[256+c00+16] = (v2f){S.y, S.w};
  }
}

// head MLP: 4 graphs/block, 512 blocks (2 blocks/CU, 8 waves/CU).
// Pooled tile staged in LDS poolT[k][4] (v4f broadcast reads). Each stage's
// k-loop manually unrolled x4 with batched weight loads (>=4 loads in flight).
__global__ void k_head(const float* __restrict__ pool,
   const float* __restrict__ gf,
   const float* __restrict__ gc_w, const float* __restrict__ gc_b,
   const float* __restrict__ gf1_w, const float* __restrict__ gf1_b,
   const float* __restrict__ gf2_w, const float* __restrict__ gf2_b,
   const float* __restrict__ p1_w, const float* __restrict__ p1_b,
   const float* __restrict__ p2_w, const float* __restrict__ p2_b,
   const float* __restrict__ p3_w, const float* __restrict__ p3_b,
   float* __restrict__ out){
  __shared__ float poolT[384*4];   // [k][g]
  __shared__ float hid1s[64*4];
  __shared__ float partial[128*4]; // v4f per c
  __shared__ float combT[192*4];
  __shared__ float r1T[128*4];
  __shared__ float ppb[3*64*4];
  __shared__ float r2T[64*4];
  int t = threadIdx.x;
  int g0 = blockIdx.x*4;

  // stage pooled tile: poolT[k*4+g] = pool[(g0+g)*384+k]
  for(int idx=t; idx<1536; idx+=256)
    poolT[idx] = pool[(size_t)(g0+(idx&3))*384 + (idx>>2)];
  // glob hid1 (no dep on poolT)
  {
    int c=t&63, g=t>>6;
    float a = gf1_b[c];
    #pragma unroll
    for(int i=0;i<10;++i) a += gf[(size_t)(g0+g)*10+i]*gf1_w[i*64+c];
    hid1s[c*4+g] = fmaxf(a,0.f);
  }
  __syncthreads();

  int c = t&127, half = t>>7;
  const v4f* poolv = (const v4f*)poolT;
  const v4f* combv = (const v4f*)combT;
  const v4f* r1v = (const v4f*)r1T;

  // ---- gc: 384-k split in 2 halves of 192, unroll 4 ----
  v4f acc = {0.f,0.f,0.f,0.f};
  {
    int kb = half*192;
    for(int kk=0; kk<192; kk+=4){
      int k = kb+kk;
      float w0 = gc_w[(k+0)*128+c];
      float w1 = gc_w[(k+1)*128+c];
      float w2 = gc_w[(k+2)*128+c];
      float w3 = gc_w[(k+3)*128+c];
      v4f p0=poolv[k+0], p1=poolv[k+1], p2=poolv[k+2], p3=poolv[k+3];
      acc += p0*w0; acc += p1*w1; acc += p2*w2; acc += p3*w3;
    }
  }
  // gf2 -> combT[128..191]
  {
    int cc=t&63, g=t>>6;
    float a = gf2_b[cc];
    #pragma unroll 4
    for(int k=0;k<64;++k) a += hid1s[k*4+g]*gf2_w[k*64+cc];
    combT[(128+cc)*4+g] = a;
  }
  if(half==1) *(v4f*)&partial[c*4] = acc;
  __syncthreads();
  if(half==0){
    v4f pb = *(const v4f*)&partial[c*4];
    float bias = gc_b[c];
    v4f r;
    r.x = fmaxf(acc.x+pb.x+bias, 0.f);
    r.y = fmaxf(acc.y+pb.y+bias, 0.f);
    r.z = fmaxf(acc.z+pb.z+bias, 0.f);
    r.w = fmaxf(acc.w+pb.w+bias, 0.f);
    *(v4f*)&combT[c*4] = r;
  }
  __syncthreads();

  // ---- p1: 192-k split in 2 halves of 96, unroll 4 ----
  v4f a1 = {0.f,0.f,0.f,0.f};
  {
    int kb = half*96;
    for(int kk=0; kk<96; kk+=4){
      int k = kb+kk;
      float w0 = p1_w[(k+0)*128+c];
      float w1 = p1_w[(k+1)*128+c];
      float w2 = p1_w[(k+2)*128+c];
      float w3 = p1_w[(k+3)*128+c];
      v4f p0=combv[k+0], p1=combv[k+1], p2=combv[k+2], p3=combv[k+3];
      a1 += p0*w0; a1 += p1*w1; a1 += p2*w2; a1 += p3*w3;
    }
  }
  if(half==1) *(v4f*)&partial[c*4] = a1;
  __syncthreads();
  if(half==0){
    v4f pb = *(const v4f*)&partial[c*4];
    float b1 = p1_b[c];
    v4f r;
    r.x = fmaxf(a1.x+pb.x+b1, 0.f);
    r.y = fmaxf(a1.y+pb.y+b1, 0.f);
    r.z = fmaxf(a1.z+pb.z+b1, 0.f);
    r.w = fmaxf(a1.w+pb.w+b1, 0.f);
    *(v4f*)&r1T[c*4] = r;
  }
  __syncthreads();

  // ---- p2: 128-k split in 4 quarters of 32, unroll 4 ----
  {
    int c2=t&63, qd=t>>6;
    v4f a2 = {0.f,0.f,0.f,0.f};
    int kb = qd*32;
    for(int kk=0; kk<32; kk+=4){
      int k = kb+kk;
      float w0 = p2_w[(k+0)*64+c2];
      float w1 = p2_w[(k+1)*64+c2];
      float w2 = p2_w[(k+2)*64+c2];
      float w3 = p2_w[(k+3)*64+c2];
      v4f p0=r1v[k+0], p1=r1v[k+1], p2=r1v[k+2], p3=r1v[k+3];
      a2 += p0*w0; a2 += p1*w1; a2 += p2*w2; a2 += p3*w3;
    }
    if(qd>0) *(v4f*)&ppb[((qd-1)*64+c2)*4] = a2;
    __syncthreads();
    if(qd==0){
      v4f q1 = *(const v4f*)&ppb[(0*64+c2)*4];
      v4f q2 = *(const v4f*)&ppb[(1*64+c2)*4];
      v4f q3 = *(const v4f*)&ppb[(2*64+c2)*4];
      float b2 = p2_b[c2];
      v4f r;
      r.x = fmaxf(a2.x+q1.x+q2.x+q3.x+b2, 0.f);
      r.y = fmaxf(a2.y+q1.y+q2.y+q3.y+b2, 0.f);
      r.z = fmaxf(a2.z+q1.z+q2.z+q3.z+b2, 0.f);
      r.w = fmaxf(a2.w+q1.w+q2.w+q3.w+b2, 0.f);
      *(v4f*)&r2T[c2*4] = r;
    }
    __syncthreads();
  }

  // ---- p3 ----
  if(t < 20){
    int g = t/5, o = t%5;
    float a = p3_b[o];
    #pragma unroll 4
    for(int k=0;k<64;++k) a += r2T[k*4+g]*p3_w[k*TOUT+o];
    out[(size_t)(g0+g)*TOUT+o] = a;
  }
}

extern "C" void kernel_launch(void* const* d_in, const int* in_sizes, int n_in,
                              void* d_out, int out_size, void* d_ws, size_t ws_size,
                              hipStream_t stream){
  (void)in_sizes; (void)n_in; (void)out_size; (void)ws_size;
  const float* x        = (const float*)d_in[0];
  const int*   ei       = (const int*)d_in[1];
  const float* ea       = (const float*)d_in[2];
  const int*   batch    = (const int*)d_in[3];
  const float* gfin     = (const float*)d_in[4];
  const float* node_w   = (const float*)d_in[5];
  const float* node_b   = (const float*)d_in[6];
  const float* edge_w   = (const float*)d_in[7];
  const float* edge_b   = (const float*)d_in[8];
  const float* gat_lin_w  = (const float*)d_in[9];
  const float* gat_edge_w = (const float*)d_in[10];
  const float* att_src  = (const float*)d_in[11];
  const float* att_dst  = (const float*)d_in[12];
  const float* att_edge = (const float*)d_in[13];
  const float* gat_bias = (const float*)d_in[14];
  const float* bn_gamma = (const float*)d_in[15];
  const float* bn_beta  = (const float*)d_in[16];
  const float* bn_mean  = (const float*)d_in[17];
  const float* bn_var   = (const float*)d_in[18];
  const float* gc_w = (const float*)d_in[19];
  const float* gc_b = (const float*)d_in[20];
  const float* gf1_w = (const float*)d_in[21];
  const float* gf1_b = (const float*)d_in[22];
  const float* gf2_w = (const float*)d_in[23];
  const float* gf2_b = (const float*)d_in[24];
  const float* p1_w = (const float*)d_in[25];
  const float* p1_b = (const float*)d_in[26];
  const float* p2_w = (const float*)d_in[27];
  const float* p2_b = (const float*)d_in[28];
  const float* p3_w = (const float*)d_in[29];
  const float* p3_b = (const float*)d_in[30];
  float* out = (float*)d_out;

  char* w = (char*)d_ws;
  size_t o = 0;
  auto carve = [&](size_t bytes)->char*{
    char* p = w + o; o += (bytes + 255) & ~(size_t)255; return p;
  };
  unsigned* xhb = (unsigned*)carve((size_t)N_NODES*64*4);
  unsigned* h16 = (unsigned*)carve((size_t)N_NODES*64*4);
  float* ea_csr = (float*)carve((size_t)N_EDGES*4*4);
  float* asad   = (float*)carve((size_t)N_NODES*8*4);
  int* deg      = (int*)carve((size_t)N_NODES*4);
  int* rowptr   = (int*)carve((size_t)(N_NODES+1)*4);
  int* fill     = (int*)carve((size_t)N_NODES*4);
  int* csr_src  = (int*)carve((size_t)N_EDGES*4);
  int* part     = (int*)carve(1024*4);
  float* mebuf  = (float*)carve(64*4);
  float* bnA    = (float*)carve((size_t)NLAYER*HID*4);
  float* bnS    = (float*)carve((size_t)NLAYER*HID*4);
  unsigned short* whi = (unsigned short*)carve(65536*2);
  unsigned short* whiE = (unsigned short*)carve(8192*2);
  unsigned short* wloE = (unsigned short*)carve(8192*2);
  float* pool   = (float*)carve((size_t)N_GRAPHS*384*4);

  // setup: mebuf + BNfold + w_ext + wswz + zero(deg,fill) + hinit
  k_setup<<<1688 + HINIT_BLOCKS, 256, 0, stream>>>(gat_edge_w, att_edge, edge_w, edge_b,
        gat_bias, bn_gamma, bn_beta, bn_mean, bn_var,
        gat_lin_w, att_src, att_dst, x, node_w, node_b, h16,
        mebuf, bnA, bnS, whiE, wloE, whi, deg, fill);
  k_deg<<<(N_EDGES+255)/256, 256, 0, stream>>>(ei, deg);
  k_scan1<<<NB,256,0,stream>>>(deg, part);
  k_scan3<<<NB,256,0,stream>>>(deg, part, rowptr);

  for(int l=0;l<NLAYER;++l){
    int gb = (l==0) ? GEMM_BLOCKS + (N_EDGES+255)/256 : GEMM_BLOCKS;
    k_gemm<<<gb,256,0,stream>>>((const unsigned short*)h16,
        whi + l*16384, whiE + l*2048, wloE + l*2048,
        xhb, asad, ei, ea, rowptr, fill, csr_src, ea_csr);
    k_aggr<<<AGGR_BLOCKS,256,0,stream>>>(xhb, asad, ea_csr, mebuf,
        rowptr, csr_src, bnA + l*128, bnS + l*128, h16, l);
  }

  k_pool<<<N_GRAPHS,256,0,stream>>>(h16, batch, pool);
  k_head<<<N_GRAPHS/4,256,0,stream>>>(pool, gfin, gc_w, gc_b, gf1_w, gf1_b,
        gf2_w, gf2_b, p1_w, p1_b, p2_w, p2_b, p3_w, p3_b, out);
}